// Round 4
// baseline (358.994 us; speedup 1.0000x reference)
//
#include <hip/hip_runtime.h>
#include <hip/hip_bf16.h>
#include <math.h>

// Problem constants
#define BATCH 1024
#define FEAT  2048
#define NCLS  11003
#define NPAD  11008      // 86 * 128
#define NT1   86         // N tiles for gemm1
#define NPART (NT1 * 2)  // psum partials per row (2 waves in N per tile)
#define M1    2048       // stacked [v; t]
#define C_SCALE  28.0f
#define C_ALPHA  0.6f
#define C_BETA   0.4f
#define C_SPOS   10.0f
#define C_SNEG   40.0f
#define XSCALE   16.0f              // Xn pre-scale into e4m3 normal range
#define SCL1     (C_SCALE / XSCALE) // logit = SCL1 * rcol * acc
#define SIMSCL   (1.0f / (XSCALE * XSCALE))

typedef float floatx4 __attribute__((ext_vector_type(4)));
typedef unsigned char u8;

// ---- workspace layout (bytes) ----
#define O_ALIGN  ((size_t)0)         // f32 align_sum
#define O_INST   ((size_t)64)        // f32 instance-CE sum
#define O_COLSQ  ((size_t)256)       // NPAD f32  (ends 44288)
#define O_XN     ((size_t)44288)     // 2048*2048 fp8 (normalized [v;t], x16)
#define O_WT     ((size_t)4238592)   // NPAD*2048 fp8 (W^T, raw values)
#define O_PSUM   ((size_t)26782976)  // 2048*NPART f32
#define O_LL     ((size_t)28192000)  // 2048 f32 label logits
// zeroed prefix: [0, O_XN)

#define PREP_WBLOCKS (43 * 32)       // W-prep blocks: 43 c-groups x 32 f-groups
#define PREP_TOTAL   (PREP_WBLOCKS + M1)

__device__ inline float softplusf(float x) {
    return (x > 20.f) ? x : log1pf(expf(x));
}

// async 16B global -> LDS (wave-uniform base + lane*16; layout is lane-linear)
__device__ inline void gll16(const void* g, void* l) {
    __builtin_amdgcn_global_load_lds(
        (const __attribute__((address_space(1))) unsigned int*)g,
        (__attribute__((address_space(3))) unsigned int*)l, 16, 0, 0);
}

__device__ inline unsigned int pack4_fp8(float a, float b, float c, float d) {
    unsigned int p = __builtin_amdgcn_cvt_pk_fp8_f32(a, b, 0, false);
    p = __builtin_amdgcn_cvt_pk_fp8_f32(c, d, p, true);
    return p;  // bytes: a,b,c,d (little-endian)
}

// ---------------- fused prep ----------------
// blocks [0, PREP_WBLOCKS): W column sumsq + fp8 transpose, 256 classes x 64 feats
// blocks [PREP_WBLOCKS, +M1): row-normalize [v; t] -> fp8 (x16)
__global__ __launch_bounds__(256) void k_prep(const float* __restrict__ vis,
                                              const float* __restrict__ txt,
                                              const float* __restrict__ W,
                                              u8* __restrict__ Xn,
                                              u8* __restrict__ WT,
                                              float* __restrict__ colsq) {
    int t = threadIdx.x;
    if (blockIdx.x < PREP_WBLOCKS) {
        int c0 = (blockIdx.x / 32) * 256, f0 = (blockIdx.x % 32) * 64;
        int c = c0 + t;
        bool live = (c < NCLS);
        float part = 0.f;
        unsigned int packs[16];
        #pragma unroll
        for (int g = 0; g < 16; ++g) {
            float w[4];
            #pragma unroll
            for (int u = 0; u < 4; ++u) {
                w[u] = live ? W[(size_t)(f0 + g*4 + u) * NCLS + c] : 0.f;
                part += w[u] * w[u];
            }
            packs[g] = pack4_fp8(w[0], w[1], w[2], w[3]);
        }
        if (live) atomicAdd(&colsq[c], part);
        uint4* dst = (uint4*)(WT + (size_t)c * FEAT + f0);
        #pragma unroll
        for (int q = 0; q < 4; ++q)
            dst[q] = make_uint4(packs[4*q], packs[4*q+1], packs[4*q+2], packs[4*q+3]);
    } else {
        int r = blockIdx.x - PREP_WBLOCKS;
        const float* src = (r < BATCH) ? (vis + (size_t)r * FEAT)
                                       : (txt + (size_t)(r - BATCH) * FEAT);
        float4 x0 = ((const float4*)src)[t];
        float4 x1 = ((const float4*)src)[t + 256];
        float ss = x0.x*x0.x + x0.y*x0.y + x0.z*x0.z + x0.w*x0.w
                 + x1.x*x1.x + x1.y*x1.y + x1.z*x1.z + x1.w*x1.w;
        __shared__ float sb[256];
        sb[t] = ss; __syncthreads();
        for (int s = 128; s > 0; s >>= 1) { if (t < s) sb[t] += sb[t + s]; __syncthreads(); }
        float rn = rsqrtf(sb[0]) * XSCALE;
        unsigned int* dst = (unsigned int*)(Xn + (size_t)r * FEAT);
        dst[t]       = pack4_fp8(x0.x*rn, x0.y*rn, x0.z*rn, x0.w*rn);
        dst[t + 256] = pack4_fp8(x1.x*rn, x1.y*rn, x1.z*rn, x1.w*rn);
    }
}

// ---------------- fused GEMM: lse tiles (y<86) + sim tiles (y>=86) ----------------
// 128x128 tile, 4 waves 2x2, 4x4 of 16x16x32 fp8 MFMA. global_load_lds staging,
// LDS chunk t (16B) at byte t*16 = row (t>>1)*32B + (t&1)*16B.
__global__ __launch_bounds__(256) void k_gemm(const u8* __restrict__ Xn,
                                              const u8* __restrict__ WT,
                                              const float* __restrict__ colsq,
                                              const int* __restrict__ labels,
                                              float* __restrict__ psum,
                                              float* __restrict__ ll,
                                              float* __restrict__ align_sum) {
    __shared__ u8 As[128 * 32], Bs[128 * 32];
    floatx4 acc[4][4] = {};
    const int t = threadIdx.x;
    const bool is_sim = (blockIdx.y >= NT1);
    int m0, n0;
    const u8 *A, *B;
    if (!is_sim) {
        m0 = blockIdx.x * 128; n0 = blockIdx.y * 128;
        A = Xn; B = WT;
    } else {
        int s = (blockIdx.y - NT1) * 16 + blockIdx.x;   // 0..63
        m0 = (s >> 3) * 128; n0 = (s & 7) * 128;
        A = Xn; B = Xn + (size_t)BATCH * FEAT;
    }
    const u8* Ag = A + (size_t)(m0 + (t >> 1)) * FEAT + (t & 1) * 16;
    const u8* Bg = B + (size_t)(n0 + (t >> 1)) * FEAT + (t & 1) * 16;
    u8* lA = As + t * 16;
    u8* lB = Bs + t * 16;

    const int wave = t >> 6, lane = t & 63;
    const int wm = wave >> 1, wn = wave & 1;
    const int quad = lane >> 4, l16 = lane & 15;
    const long* Ard[4]; const long* Brd[4];
    #pragma unroll
    for (int i = 0; i < 4; ++i) {
        Ard[i] = (const long*)(As + (wm*64 + i*16 + l16) * 32 + quad * 8);
        Brd[i] = (const long*)(Bs + (wn*64 + i*16 + l16) * 32 + quad * 8);
    }
    for (int kt = 0; kt < FEAT / 32; ++kt) {
        __syncthreads();
        gll16(Ag, lA);
        gll16(Bg, lB);
        Ag += 32; Bg += 32;
        __syncthreads();
        long af[4], bfr[4];
        #pragma unroll
        for (int i = 0; i < 4; ++i) { af[i] = *Ard[i]; bfr[i] = *Brd[i]; }
        #pragma unroll
        for (int i = 0; i < 4; ++i)
            #pragma unroll
            for (int j = 0; j < 4; ++j)
                acc[i][j] = __builtin_amdgcn_mfma_f32_16x16x32_fp8_fp8(af[i], bfr[j], acc[i][j], 0, 0, 0);
    }

    if (!is_sim) {
        // ---- LSE epilogue: fixed-max sum of exp(logit - 28) + label-logit scatter ----
        float rcol[4]; bool val[4]; int ncol[4];
        #pragma unroll
        for (int j = 0; j < 4; ++j) {
            ncol[j] = n0 + wn*64 + j*16 + l16;
            val[j] = (ncol[j] < NCLS);
            rcol[j] = val[j] ? (SCL1 * rsqrtf(colsq[ncol[j]])) : 0.f;
        }
        const int pidx = blockIdx.y * 2 + wn;
        #pragma unroll
        for (int i = 0; i < 4; ++i) {
            #pragma unroll
            for (int reg = 0; reg < 4; ++reg) {
                int m = m0 + wm*64 + i*16 + quad*4 + reg;
                int lm = labels[m & (BATCH - 1)];
                float s = 0.f;
                #pragma unroll
                for (int j = 0; j < 4; ++j) {
                    if (val[j]) {
                        float v = acc[i][j][reg] * rcol[j];
                        if (ncol[j] == lm) ll[m] = v;
                        s += __expf(v - C_SCALE);
                    }
                }
                for (int off = 1; off < 16; off <<= 1) s += __shfl_xor(s, off);
                if (l16 == 0) psum[(size_t)m * NPART + pidx] = s;
            }
        }
    } else {
        // ---- sim epilogue: masked softplus sum ----
        int ln[4];
        #pragma unroll
        for (int j = 0; j < 4; ++j) ln[j] = labels[n0 + wn*64 + j*16 + l16];
        float tot = 0.f;
        #pragma unroll
        for (int i = 0; i < 4; ++i) {
            #pragma unroll
            for (int reg = 0; reg < 4; ++reg) {
                int m = m0 + wm*64 + i*16 + quad*4 + reg;
                int lm = labels[m];
                #pragma unroll
                for (int j = 0; j < 4; ++j) {
                    float s = acc[i][j][reg] * SIMSCL;
                    float arg = (lm == ln[j]) ? (-C_SPOS * (s - C_ALPHA))
                                              : ( C_SNEG * (s - C_BETA));
                    tot += softplusf(arg);
                }
            }
        }
        for (int off = 1; off < 64; off <<= 1) tot += __shfl_xor(tot, off);
        if (lane == 0) atomicAdd(align_sum, tot);
    }
}

// ---------------- merge psum partials -> CE sum (atomic) ----------------
__global__ __launch_bounds__(256) void k_merge(const float* __restrict__ psum,
                                               const float* __restrict__ ll,
                                               float* __restrict__ inst_sum) {
    int r = blockIdx.x, t = threadIdx.x;
    float sm = (t < NPART) ? psum[(size_t)r * NPART + t] : 0.f;
    __shared__ float sb[256];
    sb[t] = sm; __syncthreads();
    for (int s = 128; s > 0; s >>= 1) { if (t < s) sb[t] += sb[t+s]; __syncthreads(); }
    if (t == 0) atomicAdd(inst_sum, C_SCALE + logf(sb[0]) - ll[r]);
}

// ---------------- final: two scalars ----------------
__global__ __launch_bounds__(64) void k_final(const float* __restrict__ inst_sum,
                                              const float* __restrict__ align_sum,
                                              float* __restrict__ out) {
    if (threadIdx.x == 0) {
        out[0] = inst_sum[0] / (float)BATCH;
        out[1] = align_sum[0] * 2.f / (float)BATCH;
    }
}

extern "C" void kernel_launch(void* const* d_in, const int* in_sizes, int n_in,
                              void* d_out, int out_size, void* d_ws, size_t ws_size,
                              hipStream_t stream) {
    const float* vis    = (const float*)d_in[0];
    const float* txt    = (const float*)d_in[1];
    const int*   labels = (const int*)  d_in[2];
    const float* W      = (const float*)d_in[3];
    float* out = (float*)d_out;
    char*  ws  = (char*)d_ws;

    float* align_sum = (float*)(ws + O_ALIGN);
    float* inst_sum  = (float*)(ws + O_INST);
    float* colsq     = (float*)(ws + O_COLSQ);
    u8* Xn = (u8*)(ws + O_XN);
    u8* WT = (u8*)(ws + O_WT);
    float* psum = (float*)(ws + O_PSUM);
    float* ll   = (float*)(ws + O_LL);

    hipMemsetAsync(ws, 0, O_XN, stream);  // zero align/inst/colsq

    k_prep <<<dim3(PREP_TOTAL), 256, 0, stream>>>(vis, txt, W, Xn, WT, colsq);
    k_gemm <<<dim3(M1 / 128, NT1 + 4), 256, 0, stream>>>(Xn, WT, colsq, labels,
                                                         psum, ll, align_sum);
    k_merge<<<dim3(M1), 256, 0, stream>>>(psum, ll, inst_sum);
    k_final<<<dim3(1), 64, 0, stream>>>(inst_sum, align_sum, out);
}

// Round 5
// 317.235 us; speedup vs baseline: 1.1316x; 1.1316x over previous
//
#include <hip/hip_runtime.h>
#include <hip/hip_bf16.h>
#include <math.h>

// Problem constants
#define BATCH 1024
#define FEAT  2048
#define NCLS  11003
#define NPAD  11008      // 86 * 128
#define NT1   86         // N tiles for gemm1
#define NPART (NT1 * 2)  // psum partials per row (2 waves in N per tile)
#define M1    2048       // stacked [v; t]
#define C_SCALE  28.0f
#define C_ALPHA  0.6f
#define C_BETA   0.4f
#define C_SPOS   10.0f
#define C_SNEG   40.0f
#define XSCALE   16.0f              // Xn pre-scale into e4m3 normal range
#define SCL1     (C_SCALE / XSCALE) // logit = SCL1 * rcol * acc
#define SIMSCL   (1.0f / (XSCALE * XSCALE))

typedef float floatx4 __attribute__((ext_vector_type(4)));
typedef unsigned char u8;

// ---- workspace layout (bytes) ----
#define O_ALIGN  ((size_t)0)         // f32 align_sum
#define O_INST   ((size_t)64)        // f32 instance-CE sum
#define O_COLSQ  ((size_t)256)       // NPAD f32  (ends 44288)
#define O_XN     ((size_t)44288)     // 2048*2048 fp8 (normalized [v;t], x16)
#define O_WT     ((size_t)4238592)   // NPAD*2048 fp8 (W^T, raw values)
#define O_PSUM   ((size_t)26782976)  // 2048*NPART f32
#define O_LL     ((size_t)28192000)  // 2048 f32 label logits
// zeroed prefix: [0, O_XN)

#define PREP_WBLOCKS (172 * 32)      // 64c x 64f tiles
#define PREP_TOTAL   (PREP_WBLOCKS + M1)

__device__ inline float softplusf(float x) {
    return (x > 20.f) ? x : log1pf(expf(x));
}

// async 16B global -> LDS (wave-uniform base + lane*16; layout is lane-linear)
__device__ inline void gll16(const void* g, void* l) {
    __builtin_amdgcn_global_load_lds(
        (const __attribute__((address_space(1))) unsigned int*)g,
        (__attribute__((address_space(3))) unsigned int*)l, 16, 0, 0);
}

__device__ inline unsigned int pack4_fp8(float a, float b, float c, float d) {
    unsigned int p = __builtin_amdgcn_cvt_pk_fp8_f32(a, b, 0, false);
    p = __builtin_amdgcn_cvt_pk_fp8_f32(c, d, p, true);
    return p;  // bytes: a,b,c,d
}

// XOR swizzle on 16B-chunk index (self-inverse): mixes row bits into bank-group bits
__device__ inline int swz(int c) { return c ^ ((c >> 4) & 7); }

// ---------------- fused prep ----------------
// blocks [0, PREP_WBLOCKS): W 64c x 64f: column sumsq + fp8 transpose via LDS
// blocks [PREP_WBLOCKS, +M1): row-normalize [v; t] -> fp8 (x16)
__global__ __launch_bounds__(256) void k_prep(const float* __restrict__ vis,
                                              const float* __restrict__ txt,
                                              const float* __restrict__ W,
                                              u8* __restrict__ Xn,
                                              u8* __restrict__ WT,
                                              float* __restrict__ colsq) {
    int t = threadIdx.x;
    if (blockIdx.x < PREP_WBLOCKS) {
        __shared__ u8 tile[64][80];      // 80: 16B-aligned row stride, bank spread
        __shared__ float cp[4][64];
        int c0 = (blockIdx.x % 172) * 64, f0 = (blockIdx.x / 172) * 64;
        int tr = t >> 6, tc = t & 63;
        int c = c0 + tc;
        bool live = (c < NCLS);
        float part = 0.f;
        #pragma unroll
        for (int rr = tr; rr < 64; rr += 4) {
            float w = live ? W[(size_t)(f0 + rr) * NCLS + c] : 0.f;
            part += w * w;
            tile[rr][tc] = (u8)(__builtin_amdgcn_cvt_pk_fp8_f32(w, 0.f, 0, false) & 0xff);
        }
        cp[tr][tc] = part;
        __syncthreads();
        if (tr == 0 && live)
            atomicAdd(&colsq[c], cp[0][tc] + cp[1][tc] + cp[2][tc] + cp[3][tc]);
        // coalesced WT write: 4 lanes x 16B = 64B contiguous per class row
        int cc = t >> 2, q = t & 3;
        uint4 vv = *(const uint4*)&tile[cc][q * 16];
        // transpose happened logically: tile[f][c] -> need tile[c][f]; gather 16 f-bytes
        u8 tmp[16];
        #pragma unroll
        for (int u = 0; u < 16; ++u) tmp[u] = tile[q * 16 + u][cc];
        *(uint4*)&WT[(size_t)(c0 + cc) * FEAT + f0 + q * 16] = *(uint4*)tmp;
        (void)vv;
    } else {
        int r = blockIdx.x - PREP_WBLOCKS;
        const float* src = (r < BATCH) ? (vis + (size_t)r * FEAT)
                                       : (txt + (size_t)(r - BATCH) * FEAT);
        float4 x0 = ((const float4*)src)[t];
        float4 x1 = ((const float4*)src)[t + 256];
        float ss = x0.x*x0.x + x0.y*x0.y + x0.z*x0.z + x0.w*x0.w
                 + x1.x*x1.x + x1.y*x1.y + x1.z*x1.z + x1.w*x1.w;
        __shared__ float sb[256];
        sb[t] = ss; __syncthreads();
        for (int s = 128; s > 0; s >>= 1) { if (t < s) sb[t] += sb[t + s]; __syncthreads(); }
        float rn = rsqrtf(sb[0]) * XSCALE;
        unsigned int* dst = (unsigned int*)(Xn + (size_t)r * FEAT);
        dst[t]       = pack4_fp8(x0.x*rn, x0.y*rn, x0.z*rn, x0.w*rn);
        dst[t + 256] = pack4_fp8(x1.x*rn, x1.y*rn, x1.z*rn, x1.w*rn);
    }
}

// ---------------- fused GEMM: lse tiles (y<86) + sim tiles (y>=86) ----------------
// 128x128 tile, BK=64 fp8: 32 k-iters x 32 MFMA (16x16x32 fp8). global_load_lds
// staging with XOR-swizzled chunk placement (2-way max LDS bank aliasing).
__global__ __launch_bounds__(256) void k_gemm(const u8* __restrict__ Xn,
                                              const u8* __restrict__ WT,
                                              const float* __restrict__ colsq,
                                              const int* __restrict__ labels,
                                              float* __restrict__ psum,
                                              float* __restrict__ ll,
                                              float* __restrict__ align_sum) {
    __shared__ u8 As[128 * 64], Bs[128 * 64];   // 8 KB + 8 KB
    floatx4 acc[4][4] = {};
    const int t = threadIdx.x;
    const bool is_sim = (blockIdx.y >= NT1);
    int m0, n0;
    const u8 *A, *B;
    if (!is_sim) {
        m0 = blockIdx.x * 128; n0 = blockIdx.y * 128;
        A = Xn; B = WT;
    } else {
        int s = (blockIdx.y - NT1) * 16 + blockIdx.x;   // 0..63
        m0 = (s >> 3) * 128; n0 = (s & 7) * 128;
        A = Xn; B = Xn + (size_t)BATCH * FEAT;
    }
    // staging: LDS chunk L holds global chunk c = swz(L); two insts per side
    const int c0s = swz(t), c1s = swz(256 + t);
    const int ra0 = c0s >> 2, h0 = c0s & 3;
    const int ra1 = c1s >> 2, h1 = c1s & 3;
    const u8* Ag0 = A + (size_t)(m0 + ra0) * FEAT + h0 * 16;
    const u8* Ag1 = A + (size_t)(m0 + ra1) * FEAT + h1 * 16;
    const u8* Bg0 = B + (size_t)(n0 + ra0) * FEAT + h0 * 16;
    const u8* Bg1 = B + (size_t)(n0 + ra1) * FEAT + h1 * 16;
    u8* lA0 = As + t * 16;
    u8* lA1 = As + 4096 + t * 16;
    u8* lB0 = Bs + t * 16;
    u8* lB1 = Bs + 4096 + t * 16;

    const int wave = t >> 6, lane = t & 63;
    const int wm = wave >> 1, wn = wave & 1;
    const int quad = lane >> 4, l16 = lane & 15;
    // fragment read pointers: logical chunk c = row*4 + ksub*2 + (quad>>1)
    const long* Ard[4][2]; const long* Brd[4][2];
    #pragma unroll
    for (int i = 0; i < 4; ++i) {
        #pragma unroll
        for (int ks = 0; ks < 2; ++ks) {
            int rA = wm*64 + i*16 + l16;
            int cA = rA*4 + ks*2 + (quad >> 1);
            Ard[i][ks] = (const long*)(As + swz(cA)*16 + (quad & 1)*8);
            int rB = wn*64 + i*16 + l16;
            int cB = rB*4 + ks*2 + (quad >> 1);
            Brd[i][ks] = (const long*)(Bs + swz(cB)*16 + (quad & 1)*8);
        }
    }
    for (int kt = 0; kt < FEAT / 64; ++kt) {
        __syncthreads();
        gll16(Ag0, lA0);
        gll16(Ag1, lA1);
        gll16(Bg0, lB0);
        gll16(Bg1, lB1);
        Ag0 += 64; Ag1 += 64; Bg0 += 64; Bg1 += 64;
        __syncthreads();
        long af[4][2], bfr[4][2];
        #pragma unroll
        for (int i = 0; i < 4; ++i) {
            af[i][0] = *Ard[i][0]; af[i][1] = *Ard[i][1];
            bfr[i][0] = *Brd[i][0]; bfr[i][1] = *Brd[i][1];
        }
        #pragma unroll
        for (int ks = 0; ks < 2; ++ks)
            #pragma unroll
            for (int i = 0; i < 4; ++i)
                #pragma unroll
                for (int j = 0; j < 4; ++j)
                    acc[i][j] = __builtin_amdgcn_mfma_f32_16x16x32_fp8_fp8(
                        af[i][ks], bfr[j][ks], acc[i][j], 0, 0, 0);
    }

    if (!is_sim) {
        // ---- LSE epilogue: fixed-max sum of exp(logit - 28) + label-logit scatter ----
        float rcol[4]; bool val[4]; int ncol[4];
        #pragma unroll
        for (int j = 0; j < 4; ++j) {
            ncol[j] = n0 + wn*64 + j*16 + l16;
            val[j] = (ncol[j] < NCLS);
            rcol[j] = val[j] ? (SCL1 * rsqrtf(colsq[ncol[j]])) : 0.f;
        }
        const int pidx = blockIdx.y * 2 + wn;
        #pragma unroll
        for (int i = 0; i < 4; ++i) {
            #pragma unroll
            for (int reg = 0; reg < 4; ++reg) {
                int m = m0 + wm*64 + i*16 + quad*4 + reg;
                int lm = labels[m & (BATCH - 1)];
                float s = 0.f;
                #pragma unroll
                for (int j = 0; j < 4; ++j) {
                    if (val[j]) {
                        float v = acc[i][j][reg] * rcol[j];
                        if (ncol[j] == lm) ll[m] = v;
                        s += __expf(v - C_SCALE);
                    }
                }
                for (int off = 1; off < 16; off <<= 1) s += __shfl_xor(s, off);
                if (l16 == 0) psum[(size_t)m * NPART + pidx] = s;
            }
        }
    } else {
        // ---- sim epilogue: masked softplus sum ----
        int ln[4];
        #pragma unroll
        for (int j = 0; j < 4; ++j) ln[j] = labels[n0 + wn*64 + j*16 + l16];
        float tot = 0.f;
        #pragma unroll
        for (int i = 0; i < 4; ++i) {
            #pragma unroll
            for (int reg = 0; reg < 4; ++reg) {
                int m = m0 + wm*64 + i*16 + quad*4 + reg;
                int lm = labels[m];
                #pragma unroll
                for (int j = 0; j < 4; ++j) {
                    float s = acc[i][j][reg] * SIMSCL;
                    float arg = (lm == ln[j]) ? (-C_SPOS * (s - C_ALPHA))
                                              : ( C_SNEG * (s - C_BETA));
                    tot += softplusf(arg);
                }
            }
        }
        for (int off = 1; off < 64; off <<= 1) tot += __shfl_xor(tot, off);
        if (lane == 0) atomicAdd(align_sum, tot);
    }
}

// ---------------- merge psum partials -> CE sum (atomic) ----------------
__global__ __launch_bounds__(256) void k_merge(const float* __restrict__ psum,
                                               const float* __restrict__ ll,
                                               float* __restrict__ inst_sum) {
    int r = blockIdx.x, t = threadIdx.x;
    float sm = (t < NPART) ? psum[(size_t)r * NPART + t] : 0.f;
    __shared__ float sb[256];
    sb[t] = sm; __syncthreads();
    for (int s = 128; s > 0; s >>= 1) { if (t < s) sb[t] += sb[t+s]; __syncthreads(); }
    if (t == 0) atomicAdd(inst_sum, C_SCALE + logf(sb[0]) - ll[r]);
}

// ---------------- final: two scalars ----------------
__global__ __launch_bounds__(64) void k_final(const float* __restrict__ inst_sum,
                                              const float* __restrict__ align_sum,
                                              float* __restrict__ out) {
    if (threadIdx.x == 0) {
        out[0] = inst_sum[0] / (float)BATCH;
        out[1] = align_sum[0] * 2.f / (float)BATCH;
    }
}

extern "C" void kernel_launch(void* const* d_in, const int* in_sizes, int n_in,
                              void* d_out, int out_size, void* d_ws, size_t ws_size,
                              hipStream_t stream) {
    const float* vis    = (const float*)d_in[0];
    const float* txt    = (const float*)d_in[1];
    const int*   labels = (const int*)  d_in[2];
    const float* W      = (const float*)d_in[3];
    float* out = (float*)d_out;
    char*  ws  = (char*)d_ws;

    float* align_sum = (float*)(ws + O_ALIGN);
    float* inst_sum  = (float*)(ws + O_INST);
    float* colsq     = (float*)(ws + O_COLSQ);
    u8* Xn = (u8*)(ws + O_XN);
    u8* WT = (u8*)(ws + O_WT);
    float* psum = (float*)(ws + O_PSUM);
    float* ll   = (float*)(ws + O_LL);

    hipMemsetAsync(ws, 0, O_XN, stream);  // zero align/inst/colsq

    k_prep <<<dim3(PREP_TOTAL), 256, 0, stream>>>(vis, txt, W, Xn, WT, colsq);
    k_gemm <<<dim3(M1 / 128, NT1 + 4), 256, 0, stream>>>(Xn, WT, colsq, labels,
                                                         psum, ll, align_sum);
    k_merge<<<dim3(M1), 256, 0, stream>>>(psum, ll, inst_sum);
    k_final<<<dim3(1), 64, 0, stream>>>(inst_sum, align_sum, out);
}